// Round 12
// baseline (907.456 us; speedup 1.0000x reference)
//
#include <hip/hip_runtime.h>
#include <hip/hip_bf16.h>

typedef unsigned int u32;
typedef unsigned long long u64;
typedef _Float16     f16;
typedef f16   f16x8v __attribute__((ext_vector_type(8)));
typedef f16   f16x4v __attribute__((ext_vector_type(4)));
typedef float f32x4  __attribute__((ext_vector_type(4)));

#define GX_BYTES ((size_t)65536 * 1024 * 2)

__device__ __forceinline__ float sigm(float x) {
    return __builtin_amdgcn_rcpf(1.0f + __expf(-x));
}
__device__ __forceinline__ float tanh_f(float x) {
    return 1.0f - 2.0f * __builtin_amdgcn_rcpf(__expf(2.0f * x) + 1.0f);
}
__device__ __forceinline__ f16x8v pack8(float4 a, float4 b) {
    f16x8v v;
    v[0] = (f16)a.x; v[1] = (f16)a.y; v[2] = (f16)a.z; v[3] = (f16)a.w;
    v[4] = (f16)b.x; v[5] = (f16)b.y; v[6] = (f16)b.z; v[7] = (f16)b.w;
    return v;
}

// ---------------------------------------------------------------------------
// Kernel 1: gates_x -> INTERLEAVED gx[m][unit*4+gate] (unchanged from
// round 11 — 106 us proven: interleave folded into a permuted+skewed Bs
// layout so both global sides stay contiguous). Zeroes the mailbox.
// ---------------------------------------------------------------------------
__global__ __launch_bounds__(256) void gemm_gx(
    const float* __restrict__ X,
    const float* __restrict__ Wf, const float* __restrict__ Wi,
    const float* __restrict__ Wc, const float* __restrict__ Wo,
    const float* __restrict__ bf_, const float* __restrict__ bi_,
    const float* __restrict__ bc_, const float* __restrict__ bo_,
    f16* __restrict__ gx, u32* __restrict__ hx) {
    __shared__ _Float16 As[128 * 40];
    __shared__ _Float16 Bs[128 * 40 + 32];
    __shared__ float bias_lds[128];

    const int tid = threadIdx.x;
    const int wgy = blockIdx.y;              // unit-block [32*wgy, 32*wgy+32)
    const size_t m0 = (size_t)blockIdx.x * 128;

    if (wgy == 0) {
        const int gid = blockIdx.x * 256 + tid;
        if (gid < 16384) {
            int4 z; z.x = 0; z.y = 0; z.z = 0; z.w = 0;
            ((int4*)hx)[gid] = z;
        }
    }

    const float* Wsel[4] = {Wf, Wi, Wc, Wo};
    const float* bsel[4] = {bf_, bi_, bc_, bo_};

    if (tid < 128) bias_lds[tid] = bsel[tid & 3][wgy * 32 + (tid >> 2)];

    const int rA  = tid >> 2;
    const int c8A = (tid & 3) * 8;
    const float* Ap0 = X + (m0 + rA) * 256 + c8A;
    const float* Ap1 = Ap0 + 64 * 256;

    const int gB    = tid >> 6;
    const int subB  = tid & 63;
    const int rowlB = subB >> 1;
    const int khB   = subB & 1;
    const float* BpG = Wsel[gB] + (size_t)(wgy * 32 + rowlB) * 512 + khB * 16;
    const int RB = rowlB + 32 * gB;
    _Float16* BsW = &Bs[RB * 40 + gB * 8 + khB * 16];

    const int lane = tid & 63;
    const int w    = tid >> 6;
    const int wm = w >> 1, wn = w & 1;
    const int col = lane & 15, quad = lane >> 4;

    f32x4 acc[4][4] = {};

    for (int kc = 0; kc < 8; kc++) {
        const int kk = kc * 32;
        float4 a00 = *(const float4*)(Ap0 + kk);
        float4 a01 = *(const float4*)(Ap0 + kk + 4);
        float4 a10 = *(const float4*)(Ap1 + kk);
        float4 a11 = *(const float4*)(Ap1 + kk + 4);
        float4 b0  = *(const float4*)(BpG + kk);
        float4 b1  = *(const float4*)(BpG + kk + 4);
        float4 b2  = *(const float4*)(BpG + kk + 8);
        float4 b3  = *(const float4*)(BpG + kk + 12);
        __syncthreads();
        *(f16x8v*)&As[rA * 40 + c8A]        = pack8(a00, a01);
        *(f16x8v*)&As[(rA + 64) * 40 + c8A] = pack8(a10, a11);
        *(f16x8v*)&BsW[0] = pack8(b0, b1);
        *(f16x8v*)&BsW[8] = pack8(b2, b3);
        __syncthreads();
        f16x8v a[4], b[4];
        #pragma unroll
        for (int i = 0; i < 4; i++)
            a[i] = *(const f16x8v*)&As[(wm * 64 + i * 16 + col) * 40 + quad * 8];
        #pragma unroll
        for (int jdx = 0; jdx < 4; jdx++) {
            const int cB = wn * 64 + jdx * 16 + col;
            const int R  = (cB >> 2) + ((cB & 3) << 5);
            b[jdx] = *(const f16x8v*)&Bs[R * 40 + (R >> 5) * 8 + quad * 8];
        }
        #pragma unroll
        for (int i = 0; i < 4; i++)
            #pragma unroll
            for (int jdx = 0; jdx < 4; jdx++)
                acc[i][jdx] = __builtin_amdgcn_mfma_f32_16x16x32_f16(a[i], b[jdx], acc[i][jdx], 0, 0, 0);
    }

    #pragma unroll
    for (int i = 0; i < 4; i++) {
        #pragma unroll
        for (int jdx = 0; jdx < 4; jdx++) {
            #pragma unroll
            for (int rg = 0; rg < 4; rg++) {
                const size_t m = m0 + wm * 64 + i * 16 + quad * 4 + rg;
                const int nl = wn * 64 + jdx * 16 + col;
                gx[m * 1024 + (size_t)wgy * 128 + nl] = (f16)(acc[i][jdx][rg] + bias_lds[nl]);
            }
        }
    }
}

// ---------------------------------------------------------------------------
// Kernel 2: 2-batch M-packed recurrence, wave-specialized, 2 waves/SIMD.
// 256 WGs x 512 thr (1 WG/CU). WG (p = bb>>2, j = bb&3): batches {2p,2p+1},
// units [64j, 64j+64).
//
// COMPUTE waves 0-3: wave w owns units [64j+16w, 64j+16w+16) x 4 gate-
// tiles x 8 kt = 32 MFMA/step. M = 16 rows = batch(row>>3) x 8 replicas ->
// chip-wide MFMA HALVED vs the round-9 champion; per SIMD one compute wave
// = 620 cyc (vs 1242). Lane's cell: C col = l15 (unit), reg0 row = quad*4
// -> batch quad>>1 — all 4 gates of one cell in acc[0..3][0]: single
// elementwise chain, no DPP, no gates-LDS (round-7 fixes), and 8 waves
// keep 2 waves/SIMD (round-10 fix). A-reads: lane supplies
// hbuf[batch l15>>3] — 2 distinct addrs/16-lane group, 512 B apart =
// counted-but-free 2-way alias (m136; explains rounds 7/10's benign
// conflict counters).
//
// POLL waves 4-7: 192 pollers, ONE u64 each (2 unit-adjacent tagged words,
// same batch), early-issued at step top, tight spin, stage into
// hbuf[cur] remote quarters, barrier1 — overlapped with compute phase A
// (own-quarter kt). Phase B after barrier1; elementwise; publish (quads
// 0,2 = one writer/cell); barrier2.
//
// Mailbox: per pair [slot(2)][batch(2)][unit(256)] tagged (h<<16)|(t+1),
// relaxed agent atomics (LLC-serviced), 2-slot double buffer. Fan-in-3
// reuse induction: we overwrite our tag-(t-1) words with (t+1) only after
// our polls consumed ALL peers' tag-t words (barrier1 precedes publish),
// and each peer published tag t only after finishing its tag-(t-1) polls.
// Zeroed each replay by gemm_gx (t=0 poll matches tag-0 zeros = h_0);
// spins bounded so a bug can't hang.
// ---------------------------------------------------------------------------
__global__ __launch_bounds__(512, 2) void lstm_rec(
    const float* __restrict__ Wf, const float* __restrict__ Wi,
    const float* __restrict__ Wc, const float* __restrict__ Wo,
    const f16* __restrict__ gx,
    const float* __restrict__ Wout, const float* __restrict__ bout,
    u32* hx,
    float* __restrict__ out) {
    __shared__ _Float16 hbuf[2][2][256] __attribute__((aligned(16)));

    const int tid  = threadIdx.x;
    const int bb   = blockIdx.x;
    const int p    = bb >> 2;         // batch pair {2p, 2p+1}
    const int j    = bb & 3;          // unit-quarter 0..3
    const int w    = tid >> 6;        // wave 0..7
    const int l    = tid & 63;
    const int l15  = l & 15;
    const int quad = l >> 4;
    const int arow = l15 >> 3;        // batch whose h this lane supplies (A)
    const int bl   = quad >> 1;       // batch whose cell this lane owns (C)

    // kt order: own quarter first (phase A), then remote quarters
    int ktm[8];
    ktm[0] = 2 * j; ktm[1] = 2 * j + 1;
    #pragma unroll
    for (int r = 0; r < 3; r++) {
        const int qr = (j + 1 + r) & 3;
        ktm[2 + 2 * r] = 2 * qr;
        ktm[3 + 2 * r] = 2 * qr + 1;
    }

    // ---- compute-wave state ----
    const int u = 64 * j + 16 * (w & 3) + l15;   // unit (compute waves)
    f16x8v wB[4][8];
    const f16* gxr = nullptr;
    float pf = 0.f, pi_ = 0.f, pg = 0.f, po = 0.f;
    float c = 0.0f;

    // ---- poll-wave state ----
    const int pollme = (tid >= 256 && tid < 448);
    int pB = 0, ru = 0;
    size_t poff = 0;

    if (w < 4) {
        const float* gp[4] = {Wf, Wi, Wc, Wo};
        #pragma unroll
        for (int g = 0; g < 4; g++) {
            const float* row = gp[g] + (size_t)u * 512 + 256 + quad * 8;
            #pragma unroll
            for (int idx = 0; idx < 8; idx++) {
                const int ko = ktm[idx] * 32;
                float4 x0 = *(const float4*)(row + ko);
                float4 x1 = *(const float4*)(row + ko + 4);
                wB[g][idx] = pack8(x0, x1);
            }
        }
        gxr = gx + (size_t)(2 * p + bl) * 512 * 1024 + (size_t)u * 4;
        f16x4v gv = *(const f16x4v*)gxr;             // t = 0
        pf = (float)gv[0]; pi_ = (float)gv[1];
        pg = (float)gv[2]; po  = (float)gv[3];
    } else if (pollme) {
        const int e  = tid - 256;                    // 0..191
        pB = e / 96;                                 // batch 0/1
        const int k2 = (e % 96) * 2;                 // even remote rank
        ru = k2 + (k2 >= 64 * j ? 64 : 0);           // skip own quarter
        poff = (size_t)pB * 256 + ru;                // + slot*512
    }

    // h_0 = 0 (slot 0: 512 f16 = 256 u32)
    if (tid < 256) ((u32*)&hbuf[0][0][0])[tid] = 0u;

    u32* mail = hx + (size_t)p * 1024;   // [slot(2)][batch(2)][unit(256)]

    const f32x4 Zc = {0.f, 0.f, 0.f, 0.f};

    __syncthreads();   // h_0 visible

    for (int t = 0; t < 512; t++) {
        const int cur = t & 1;
        const int nxt = cur ^ 1;

        if (w < 4) {
            // gx prefetch for next step (8 B)
            f16x4v gn = *(const f16x4v*)(gxr + (size_t)(t < 511 ? t + 1 : 511) * 1024);

            // Phase A: own-quarter kt (no remote dependence)
            const _Float16* hA = &hbuf[cur][arow][quad * 8];
            f32x4 acc[4];
            {
                f16x8v A = *(const f16x8v*)&hA[ktm[0] * 32];
                #pragma unroll
                for (int g = 0; g < 4; g++)
                    acc[g] = __builtin_amdgcn_mfma_f32_16x16x32_f16(A, wB[g][0], Zc, 0, 0, 0);
                f16x8v B = *(const f16x8v*)&hA[ktm[1] * 32];
                #pragma unroll
                for (int g = 0; g < 4; g++)
                    acc[g] = __builtin_amdgcn_mfma_f32_16x16x32_f16(B, wB[g][1], acc[g], 0, 0, 0);
            }

            __syncthreads();   // barrier1: remote quarters of h_t staged

            // Phase B: remote kt
            #pragma unroll
            for (int idx = 2; idx < 8; idx++) {
                f16x8v A = *(const f16x8v*)&hA[ktm[idx] * 32];
                #pragma unroll
                for (int g = 0; g < 4; g++)
                    acc[g] = __builtin_amdgcn_mfma_f32_16x16x32_f16(A, wB[g][idx], acc[g], 0, 0, 0);
            }

            // Elementwise: cell (batch bl, unit u); reg0 = replica row.
            float F = pf + acc[0][0];
            float I = pi_ + acc[1][0];
            float G = pg + acc[2][0];
            float O = po + acc[3][0];
            float sf = sigm(F), si = sigm(I), so = sigm(O);
            float tg = tanh_f(G);
            c = c * sf + si * tg;
            float h = tanh_f(c) * so;

            const f16 h16v = (f16)h;
            if ((quad & 1) == 0) {      // one writer per cell (quads 0, 2)
                u32 word = ((u32)__builtin_bit_cast(unsigned short, h16v) << 16)
                         | (u32)(t + 1);
                __hip_atomic_store(mail + nxt * 512 + bl * 256 + u, word,
                                   __ATOMIC_RELAXED, __HIP_MEMORY_SCOPE_AGENT);
                hbuf[nxt][bl][u] = h16v;    // own quarter for next step
            }

            pf = (float)gn[0]; pi_ = (float)gn[1];
            pg = (float)gn[2]; po  = (float)gn[3];
        } else {
            // Poll waves: early-issue, spin, stage remote quarters of h_t.
            if (pollme) {
                u64 rv = __hip_atomic_load((const u64*)(mail + cur * 512 + poff),
                                           __ATOMIC_RELAXED, __HIP_MEMORY_SCOPE_AGENT);
                const u32 want = (u32)t;
                int spin = 0;
                while ((((u32)rv & 0xFFFFu) != want ||
                        (((u32)(rv >> 32)) & 0xFFFFu) != want) && ++spin < (1 << 20))
                    rv = __hip_atomic_load((const u64*)(mail + cur * 512 + poff),
                                           __ATOMIC_RELAXED, __HIP_MEMORY_SCOPE_AGENT);
                const u32 packed = (u32)((rv >> 16) & 0xFFFFu)
                                 | (u32)(((rv >> 48) & 0xFFFFu) << 16);
                *(u32*)&hbuf[cur][pB][ru] = packed;
            }
            __syncthreads();   // barrier1 (poll side)
        }

        __syncthreads();   // barrier2: h_{t+1} own quarters visible; reuse guard
    }

    // Final: stage peers' tag-512 words (slot 0) to complete h_512.
    if (pollme) {
        u64 rv = __hip_atomic_load((const u64*)(mail + 0 * 512 + poff),
                                   __ATOMIC_RELAXED, __HIP_MEMORY_SCOPE_AGENT);
        int spin = 0;
        while ((((u32)rv & 0xFFFFu) != 512u ||
                (((u32)(rv >> 32)) & 0xFFFFu) != 512u) && ++spin < (1 << 20))
            rv = __hip_atomic_load((const u64*)(mail + 0 * 512 + poff),
                                   __ATOMIC_RELAXED, __HIP_MEMORY_SCOPE_AGENT);
        const u32 packed = (u32)((rv >> 16) & 0xFFFFu)
                         | (u32)(((rv >> 48) & 0xFFFFu) << 16);
        *(u32*)&hbuf[0][pB][ru] = packed;
    }
    __syncthreads();

    // out[2p+B, 32j:32j+32] = h_512 @ Wout^T + bout
    if (tid < 64) {
        const int B = tid >> 5;
        const int o = 32 * j + (tid & 31);
        float accv = bout[o];
        const _Float16* hr = &hbuf[0][B][0];
        const float* wr = Wout + (size_t)o * 256;
        for (int k0 = 0; k0 < 256; k0 += 8) {
            f16x8v hv = *(const f16x8v*)&hr[k0];
            float4 w0 = *(const float4*)(wr + k0);
            float4 w1 = *(const float4*)(wr + k0 + 4);
            accv += w0.x * (float)hv[0] + w0.y * (float)hv[1]
                  + w0.z * (float)hv[2] + w0.w * (float)hv[3]
                  + w1.x * (float)hv[4] + w1.y * (float)hv[5]
                  + w1.z * (float)hv[6] + w1.w * (float)hv[7];
        }
        out[(size_t)(2 * p + B) * 128 + o] = accv;
    }
}

extern "C" void kernel_launch(void* const* d_in, const int* in_sizes, int n_in,
                              void* d_out, int out_size, void* d_ws, size_t ws_size,
                              hipStream_t stream) {
    const float* x    = (const float*)d_in[0];
    const float* Wf   = (const float*)d_in[1];
    const float* bfv  = (const float*)d_in[2];
    const float* Wi   = (const float*)d_in[3];
    const float* biv  = (const float*)d_in[4];
    const float* Wc   = (const float*)d_in[5];
    const float* bcv  = (const float*)d_in[6];
    const float* Wo   = (const float*)d_in[7];
    const float* bov  = (const float*)d_in[8];
    const float* Wout = (const float*)d_in[9];
    const float* bout = (const float*)d_in[10];

    f16* gx = (f16*)d_ws;
    u32* hx = (u32*)((char*)d_ws + GX_BYTES);   // 256 KB mailbox after gx

    gemm_gx<<<dim3(512, 8), 256, 0, stream>>>(x, Wf, Wi, Wc, Wo, bfv, biv, bcv, bov, gx, hx);
    lstm_rec<<<256, 512, 0, stream>>>(Wf, Wi, Wc, Wo, gx, Wout, bout, hx, (float*)d_out);
}